// Round 6
// baseline (812.315 us; speedup 1.0000x reference)
//
#include <hip/hip_runtime.h>

// ---------------------------------------------------------------------------
// GCN forward:  relu(x@W1+b1) -> gcnconv(Wc1) -> relu -> gcnconv(Wc2) -> relu
//               -> @W2 + b2
//
// R6: (a) gemm1 256x64 tile / 8x8 microtile (halves LDS instr per FLOP; R5
//         showed gemm1 is ds_read_b128-throughput bound, 150k cyc/CU).
//     (b) CSR build via 64-node buckets: bhist rank-atomic on 1563 hot
//         counters; atomic-free bscatter into L2-resident bucket regions;
//         bsort (block per bucket) emits per-node CSR + dinv in one pass.
//     k_conv / k_agg / k_final unchanged (bf16 t', absmax 9.77e-4).
// ---------------------------------------------------------------------------

#define BCAP 1536   // LDS staging per bucket (mean 1024, sigma 32 edges)

__device__ __forceinline__ unsigned bf16_rne(float f) {
    unsigned u = __float_as_uint(f);
    return (u + 0x7fffu + ((u >> 16) & 1u)) >> 16;   // finite inputs only
}

__device__ __forceinline__ void unpack8(uint4 p, float v[8]) {
    v[0] = __uint_as_float(p.x << 16); v[1] = __uint_as_float(p.x & 0xffff0000u);
    v[2] = __uint_as_float(p.y << 16); v[3] = __uint_as_float(p.y & 0xffff0000u);
    v[4] = __uint_as_float(p.z << 16); v[5] = __uint_as_float(p.z & 0xffff0000u);
    v[6] = __uint_as_float(p.w << 16); v[7] = __uint_as_float(p.w & 0xffff0000u);
}

// ============================= bucket build ================================

__global__ __launch_bounds__(256) void k_zero_b(int* __restrict__ bcnt, int nb) {
    int i = blockIdx.x * 256 + threadIdx.x;
    if (i <= nb) bcnt[i] = 0;
}

// rank within destination bucket (bucket = col>>6); 1563 hot counters
__global__ __launch_bounds__(256) void k_bhist(const int* __restrict__ col,
                                               int* __restrict__ bcnt,
                                               int* __restrict__ rank, int ne) {
    int i = blockIdx.x * 256 + threadIdx.x;
    if (i < ne) rank[i] = atomicAdd(&bcnt[col[i] >> 6], 1);
}

// exclusive scan of bcnt[nb] -> bptr; single block, 256-wide rounds w/ carry
__global__ __launch_bounds__(256) void k_bscan(const int* __restrict__ bcnt,
                                               int* __restrict__ bptr,
                                               int* __restrict__ ptr,
                                               int nb, int n, int etot) {
    __shared__ int s[256];
    __shared__ int carry;
    const int t = threadIdx.x;
    if (t == 0) carry = 0;
    __syncthreads();
    for (int base = 0; base < nb; base += 256) {
        int i = base + t;
        int v = (i < nb) ? bcnt[i] : 0;
        s[t] = v;
        __syncthreads();
#pragma unroll
        for (int off = 1; off < 256; off <<= 1) {
            int y = (t >= off) ? s[t - off] : 0;
            __syncthreads();
            s[t] += y;
            __syncthreads();
        }
        if (i < nb) bptr[i] = carry + s[t] - v;
        __syncthreads();
        if (t == 255) carry += s[255];
        __syncthreads();
    }
    if (t == 0) { bptr[nb] = carry; ptr[n] = etot; }
}

// scatter into bucket regions (atomic-free; writes land in ~65KB hot regions)
// rec.x = row | collocal<<20 ; rec.y = ew bits
__global__ __launch_bounds__(256) void k_bscatter(const int* __restrict__ row,
                                                  const int* __restrict__ col,
                                                  const float* __restrict__ ew,
                                                  const int* __restrict__ bptr,
                                                  const int* __restrict__ rank,
                                                  int2* __restrict__ recs, int ne) {
    int i = blockIdx.x * 256 + threadIdx.x;
    if (i < ne) {
        int c = col[i];
        int pos = bptr[c >> 6] + rank[i];
        recs[pos] = make_int2(row[i] | ((c & 63) << 20), __float_as_int(ew[i]));
    }
}

// per bucket (64 nodes): order recs by node -> recs2, emit ptr[] and dinv[].
// count/scatter phases split 4 ways (quarter q = tid>>6, node l = tid&63).
__global__ __launch_bounds__(256) void k_bsort(const int2* __restrict__ recs,
                                               const int* __restrict__ bptr,
                                               int2* __restrict__ recs2,
                                               int* __restrict__ ptr,
                                               float* __restrict__ dinv, int n) {
    __shared__ int2 st[BCAP];
    __shared__ int cnt4[4][64];
    __shared__ float deg4[4][64];
    __shared__ int base[65];
    const int b = blockIdx.x;
    const int t = threadIdx.x;
    const int s0 = bptr[b], s1 = bptr[b + 1];
    const int ne = s1 - s0;
    const int S = ne < BCAP ? ne : BCAP;
    for (int i = t; i < S; i += 256) st[i] = recs[s0 + i];
    const int q = t >> 6, l = t & 63;
    __syncthreads();

    // --- count + degree (ownership scan: lane l of wave q checks quarter q) ---
    int c = 0; float d = 0.f;
    const int per = (S + 3) >> 2;
    const int qs = q * per, qe = min(qs + per, S);
    for (int i = qs; i < qe; ++i) {
        int2 r = st[i];
        if (((r.x >> 20) & 63) == l) { c++; d += __int_as_float(r.y); }
    }
    if (ne > BCAP) {   // overflow tail straight from global (rare/never)
        const int oe = ne - BCAP;
        const int perq = (oe + 3) >> 2;
        const int os = BCAP + q * perq, oeq = min(os + perq, ne);
        for (int i = os; i < oeq; ++i) {
            int2 r = recs[s0 + i];
            if (((r.x >> 20) & 63) == l) { c++; d += __int_as_float(r.y); }
        }
    }
    cnt4[q][l] = c; deg4[q][l] = d;
    __syncthreads();

    if (t < 64) {
        base[t + 1] = cnt4[0][t] + cnt4[1][t] + cnt4[2][t] + cnt4[3][t];
        int g = (b << 6) + t;
        if (g < n)
            dinv[g] = rsqrtf(1.f + deg4[0][t] + deg4[1][t] + deg4[2][t] + deg4[3][t]);
    }
    if (t == 0) base[0] = 0;
    __syncthreads();
#pragma unroll
    for (int off = 1; off < 64; off <<= 1) {   // inclusive scan over base[1..64]
        int v = 0;
        if (t < 64 && t >= off) v = base[t + 1 - off];
        __syncthreads();
        if (t < 64 && t >= off) base[t + 1] += v;
        __syncthreads();
    }
    if (t < 64) {
        int g = (b << 6) + t;
        if (g < n) ptr[g] = s0 + base[t];
    }
    __syncthreads();

    // --- scatter: thread (q,l) rewrites quarter q's matches for node l ---
    int cur = s0 + base[l];
    if (q > 0) cur += cnt4[0][l];
    if (q > 1) cur += cnt4[1][l];
    if (q > 2) cur += cnt4[2][l];
    for (int i = qs; i < qe; ++i) {
        int2 r = st[i];
        if (((r.x >> 20) & 63) == l)
            recs2[cur++] = make_int2(r.x & 0xFFFFF, r.y);
    }
    if (ne > BCAP) {
        const int oe = ne - BCAP;
        const int perq = (oe + 3) >> 2;
        const int os = BCAP + q * perq, oeq = min(os + perq, ne);
        for (int i = os; i < oeq; ++i) {
            int2 r = recs[s0 + i];
            if (((r.x >> 20) & 63) == l)
                recs2[cur++] = make_int2(r.x & 0xFFFFF, r.y);
        }
    }
}

// ============================= GEMM1 =======================================
// h = relu(x @ W1 + b1); x[N,256], W1[256,64].
// 256x64 tile, 8x8 microtile (tx=tid&7 -> cols tx*8..+7; rows j*32+ty).
// Row assignment j*32+ty keeps stride-36 a-reads conflict-free (4*ty mod 32).
__global__ __launch_bounds__(256) void k_gemm1(const float* __restrict__ x,
                                               const float* __restrict__ W,
                                               const float* __restrict__ bias,
                                               float* __restrict__ h, int n) {
    __shared__ float xs[256 * 36];   // 36 KB
    __shared__ float ws[32 * 64];    // 8 KB
    const int tid = threadIdx.x;
    const int row0 = blockIdx.x * 256;
    const int tx = tid & 7;
    const int ty = tid >> 3;
    float acc[8][8] = {};

    for (int kb = 0; kb < 8; ++kb) {
        const int k0 = kb * 32;
#pragma unroll
        for (int i = 0; i < 2; ++i) {           // W chunk 32x64
            int f = tid + i * 256;
            int kr = f >> 4, cc = (f & 15) * 4;
            *(float4*)(ws + kr * 64 + cc) =
                *(const float4*)(W + (size_t)(k0 + kr) * 64 + cc);
        }
#pragma unroll
        for (int i = 0; i < 8; ++i) {           // x tile 256x32
            int f = tid + i * 256;
            int r = f >> 3, kc = (f & 7) * 4;
            int row = row0 + r;
            float4 v = make_float4(0.f, 0.f, 0.f, 0.f);
            if (row < n) v = *(const float4*)(x + (size_t)row * 256 + k0 + kc);
            *(float4*)(xs + r * 36 + kc) = v;
        }
        __syncthreads();
#pragma unroll
        for (int kk = 0; kk < 32; kk += 4) {
            float4 a[8];
#pragma unroll
            for (int j = 0; j < 8; ++j)
                a[j] = *(const float4*)(xs + (j * 32 + ty) * 36 + kk);
            float4 b0[4], b1[4];
#pragma unroll
            for (int qq = 0; qq < 4; ++qq) {
                b0[qq] = *(const float4*)(ws + (kk + qq) * 64 + tx * 8);
                b1[qq] = *(const float4*)(ws + (kk + qq) * 64 + tx * 8 + 4);
            }
#pragma unroll
            for (int j = 0; j < 8; ++j) {
                float aj[4] = {a[j].x, a[j].y, a[j].z, a[j].w};
#pragma unroll
                for (int qq = 0; qq < 4; ++qq) {
                    acc[j][0] = fmaf(aj[qq], b0[qq].x, acc[j][0]);
                    acc[j][1] = fmaf(aj[qq], b0[qq].y, acc[j][1]);
                    acc[j][2] = fmaf(aj[qq], b0[qq].z, acc[j][2]);
                    acc[j][3] = fmaf(aj[qq], b0[qq].w, acc[j][3]);
                    acc[j][4] = fmaf(aj[qq], b1[qq].x, acc[j][4]);
                    acc[j][5] = fmaf(aj[qq], b1[qq].y, acc[j][5]);
                    acc[j][6] = fmaf(aj[qq], b1[qq].z, acc[j][6]);
                    acc[j][7] = fmaf(aj[qq], b1[qq].w, acc[j][7]);
                }
            }
        }
        __syncthreads();
    }

    float4 bb0 = *(const float4*)(bias + tx * 8);
    float4 bb1 = *(const float4*)(bias + tx * 8 + 4);
#pragma unroll
    for (int j = 0; j < 8; ++j) {
        int row = row0 + j * 32 + ty;
        if (row < n) {
            float4 o0, o1;
            o0.x = fmaxf(acc[j][0] + bb0.x, 0.f);
            o0.y = fmaxf(acc[j][1] + bb0.y, 0.f);
            o0.z = fmaxf(acc[j][2] + bb0.z, 0.f);
            o0.w = fmaxf(acc[j][3] + bb0.w, 0.f);
            o1.x = fmaxf(acc[j][4] + bb1.x, 0.f);
            o1.y = fmaxf(acc[j][5] + bb1.y, 0.f);
            o1.z = fmaxf(acc[j][6] + bb1.z, 0.f);
            o1.w = fmaxf(acc[j][7] + bb1.w, 0.f);
            *(float4*)(h + (size_t)row * 64 + tx * 8) = o0;
            *(float4*)(h + (size_t)row * 64 + tx * 8 + 4) = o1;
        }
    }
}

// ============================= Conv dense part =============================
// t'[r] = bf16( dinv[r] * (hin @ W)[r] )   -- bf16, 128 B per row
__global__ __launch_bounds__(256) void k_conv(const float* __restrict__ hin,
                                              const float* __restrict__ W,
                                              const float* __restrict__ dinv,
                                              unsigned* __restrict__ tb,
                                              int n) {
    __shared__ float xs[64 * 68];
    __shared__ float ws[64 * 64];
    const int tid = threadIdx.x;
    const int row0 = blockIdx.x * 64;
    const int tx = tid & 15, ty = tid >> 4;

    {
        const float4* src = (const float4*)W;
        float4* dst = (float4*)ws;
#pragma unroll
        for (int i = 0; i < 4; ++i) dst[tid + i * 256] = src[tid + i * 256];
    }
#pragma unroll
    for (int i = 0; i < 4; ++i) {
        int f = tid + i * 256;
        int r = f >> 4;
        int c = (f & 15) * 4;
        int row = row0 + r;
        float4 v = make_float4(0.f, 0.f, 0.f, 0.f);
        if (row < n) v = *(const float4*)(hin + (size_t)row * 64 + c);
        *(float4*)(xs + r * 68 + c) = v;
    }
    __syncthreads();

    float acc[4][4] = {};
#pragma unroll
    for (int kk = 0; kk < 64; kk += 4) {
        float4 a[4], b[4];
#pragma unroll
        for (int j = 0; j < 4; ++j)
            a[j] = *(const float4*)(xs + (ty * 4 + j) * 68 + kk);
#pragma unroll
        for (int qq = 0; qq < 4; ++qq)
            b[qq] = *(const float4*)(ws + (kk + qq) * 64 + tx * 4);
#pragma unroll
        for (int j = 0; j < 4; ++j) {
            float aj[4] = {a[j].x, a[j].y, a[j].z, a[j].w};
#pragma unroll
            for (int qq = 0; qq < 4; ++qq) {
                acc[j][0] = fmaf(aj[qq], b[qq].x, acc[j][0]);
                acc[j][1] = fmaf(aj[qq], b[qq].y, acc[j][1]);
                acc[j][2] = fmaf(aj[qq], b[qq].z, acc[j][2]);
                acc[j][3] = fmaf(aj[qq], b[qq].w, acc[j][3]);
            }
        }
    }
#pragma unroll
    for (int j = 0; j < 4; ++j) {
        int row = row0 + ty * 4 + j;
        if (row < n) {
            float dv = dinv[row];
            uint2 w;
            w.x = bf16_rne(dv * acc[j][0]) | (bf16_rne(dv * acc[j][1]) << 16);
            w.y = bf16_rne(dv * acc[j][2]) | (bf16_rne(dv * acc[j][3]) << 16);
            *(uint2*)(tb + (size_t)row * 32 + tx * 2) = w;
        }
    }
}

// ============================= CSR aggregation =============================
__global__ __launch_bounds__(256) void k_agg(const int* __restrict__ ptr,
                                             const int2* __restrict__ recs,
                                             const float* __restrict__ dinv,
                                             const float* __restrict__ bias,
                                             const uint4* __restrict__ t4,
                                             float4* __restrict__ agg4, int n) {
    const int lane = threadIdx.x & 63;
    const int c = blockIdx.x * 4 + (threadIdx.x >> 6);
    if (c >= n) return;
    const int grp = lane >> 3;
    const int f = lane & 7;

    float acc[8] = {};
    if (grp == 0) {
        float v[8];
        unpack8(t4[(size_t)c * 8 + f], v);
#pragma unroll
        for (int i = 0; i < 8; ++i) acc[i] = v[i];
    }

    const int eEnd = ptr[c + 1];
    int e = ptr[c] + grp;
    int2 rec = (e < eEnd) ? recs[e] : make_int2(0, 0);
    while (e < eEnd) {
        int2 cur = rec;
        e += 8;
        if (e < eEnd) rec = recs[e];
        uint4 p = t4[(size_t)cur.x * 8 + f];
        float w = __int_as_float(cur.y);
        float v[8];
        unpack8(p, v);
#pragma unroll
        for (int i = 0; i < 8; ++i) acc[i] = fmaf(w, v[i], acc[i]);
    }

#pragma unroll
    for (int off = 8; off < 64; off <<= 1) {
#pragma unroll
        for (int i = 0; i < 8; ++i) acc[i] += __shfl_xor(acc[i], off, 64);
    }

    if (grp == 0) {
        const float wc = dinv[c];
        float4 b0 = ((const float4*)bias)[f * 2];
        float4 b1 = ((const float4*)bias)[f * 2 + 1];
        float4 o0, o1;
        o0.x = fmaxf(fmaf(wc, acc[0], b0.x), 0.f);
        o0.y = fmaxf(fmaf(wc, acc[1], b0.y), 0.f);
        o0.z = fmaxf(fmaf(wc, acc[2], b0.z), 0.f);
        o0.w = fmaxf(fmaf(wc, acc[3], b0.w), 0.f);
        o1.x = fmaxf(fmaf(wc, acc[4], b1.x), 0.f);
        o1.y = fmaxf(fmaf(wc, acc[5], b1.y), 0.f);
        o1.z = fmaxf(fmaf(wc, acc[6], b1.z), 0.f);
        o1.w = fmaxf(fmaf(wc, acc[7], b1.w), 0.f);
        agg4[(size_t)c * 16 + f * 2] = o0;
        agg4[(size_t)c * 16 + f * 2 + 1] = o1;
    }
}

// ============================= Final GEMM ==================================
__global__ __launch_bounds__(256) void k_final(const float* __restrict__ hin,
                                               const float* __restrict__ W,
                                               const float* __restrict__ bias,
                                               float* __restrict__ out, int n) {
    __shared__ float xs[64 * 68];
    __shared__ float ws[64 * 40];
    const int tid = threadIdx.x;
    const int row0 = blockIdx.x * 64;

    for (int i = tid; i < 640; i += 256)
        ((float4*)ws)[i] = ((const float4*)W)[i];
#pragma unroll
    for (int i = 0; i < 4; ++i) {
        int f = tid + i * 256;
        int r = f >> 4;
        int c = (f & 15) * 4;
        int row = row0 + r;
        float4 v = make_float4(0.f, 0.f, 0.f, 0.f);
        if (row < n) v = *(const float4*)(hin + (size_t)row * 64 + c);
        *(float4*)(xs + r * 68 + c) = v;
    }
    __syncthreads();

    const int tx = tid & 15, ty = tid >> 4;
    if (tx < 10) {
        float acc[4][4] = {};
#pragma unroll
        for (int kk = 0; kk < 64; kk += 4) {
            float4 a[4], b[4];
#pragma unroll
            for (int j = 0; j < 4; ++j)
                a[j] = *(const float4*)(xs + (ty * 4 + j) * 68 + kk);
#pragma unroll
            for (int qq = 0; qq < 4; ++qq)
                b[qq] = *(const float4*)(ws + (kk + qq) * 40 + tx * 4);
#pragma unroll
            for (int j = 0; j < 4; ++j) {
                float aj[4] = {a[j].x, a[j].y, a[j].z, a[j].w};
#pragma unroll
                for (int qq = 0; qq < 4; ++qq) {
                    acc[j][0] = fmaf(aj[qq], b[qq].x, acc[j][0]);
                    acc[j][1] = fmaf(aj[qq], b[qq].y, acc[j][1]);
                    acc[j][2] = fmaf(aj[qq], b[qq].z, acc[j][2]);
                    acc[j][3] = fmaf(aj[qq], b[qq].w, acc[j][3]);
                }
            }
        }
        float4 bb = *(const float4*)(bias + tx * 4);
#pragma unroll
        for (int j = 0; j < 4; ++j) {
            int row = row0 + ty * 4 + j;
            if (row < n) {
                float4 o = make_float4(acc[j][0] + bb.x, acc[j][1] + bb.y,
                                       acc[j][2] + bb.z, acc[j][3] + bb.w);
                *(float4*)(out + (size_t)row * 40 + tx * 4) = o;
            }
        }
    }
}

extern "C" void kernel_launch(void* const* d_in, const int* in_sizes, int n_in,
                              void* d_out, int out_size, void* d_ws, size_t ws_size,
                              hipStream_t stream) {
    const float* x   = (const float*)d_in[0];
    const int*   ei  = (const int*)d_in[1];
    const float* ew  = (const float*)d_in[2];
    const float* W1  = (const float*)d_in[3];
    const float* b1  = (const float*)d_in[4];
    const float* Wc1 = (const float*)d_in[5];
    const float* bc1 = (const float*)d_in[6];
    const float* Wc2 = (const float*)d_in[7];
    const float* bc2 = (const float*)d_in[8];
    const float* W2  = (const float*)d_in[9];
    const float* b2  = (const float*)d_in[10];
    float* out = (float*)d_out;

    const int N = in_sizes[0] / 256;
    const int E = in_sizes[2];
    const int NB = (N + 63) >> 6;      // 64-node buckets
    const int* row = ei;
    const int* col = ei + E;

    // workspace layout:
    // recs[E int2] | recs2[E int2] | bufA[64N f] | bufB[64N f] | dinv[N f]
    //   | ptr[N+1 i] | bcnt[NB+1 i] | bptr[NB+1 i]
    // rank[E] aliases head of bufA (dead after k_bscatter, before k_gemm1).
    // bufB doubles as bf16 t' (first 32N floats).
    int2*  recs  = (int2*)d_ws;
    int2*  recs2 = recs + E;
    float* bufA  = (float*)(recs2 + E);
    float* bufB  = bufA + (size_t)N * 64;
    float* dinv  = bufB + (size_t)N * 64;
    int*   ptr   = (int*)(dinv + N);
    int*   bcnt  = ptr + N + 1;
    int*   bptr  = bcnt + NB + 1;
    int*   rank  = (int*)bufA;
    unsigned* tb = (unsigned*)bufB;

    const int gE = (E + 255) / 256;
    const int gG = (N + 63) / 64;
    const int gA = (N + 3) / 4;
    const int gG1 = (N + 255) / 256;

    // --- bucketed CSR build (shared by both convs) ---
    k_zero_b<<<(NB + 256) / 256, 256, 0, stream>>>(bcnt, NB);
    k_bhist<<<gE, 256, 0, stream>>>(col, bcnt, rank, E);
    k_bscan<<<1, 256, 0, stream>>>(bcnt, bptr, ptr, NB, N, E);
    k_bscatter<<<gE, 256, 0, stream>>>(row, col, ew, bptr, rank, recs, E);
    k_bsort<<<NB, 256, 0, stream>>>(recs, bptr, recs2, ptr, dinv, N);

    // --- layer 1: h1 = relu(x@W1+b1) -> bufA ---
    k_gemm1<<<gG1, 256, 0, stream>>>(x, W1, b1, bufA, N);

    // --- conv1 ---
    k_conv<<<gG, 256, 0, stream>>>(bufA, Wc1, dinv, tb, N);
    k_agg<<<gA, 256, 0, stream>>>(ptr, recs2, dinv, bc1, (const uint4*)tb,
                                  (float4*)bufA, N);

    // --- conv2 ---
    k_conv<<<gG, 256, 0, stream>>>(bufA, Wc2, dinv, tb, N);
    k_agg<<<gA, 256, 0, stream>>>(ptr, recs2, dinv, bc2, (const uint4*)tb,
                                  (float4*)bufA, N);

    // --- out = agg2 @ W2 + b2 ---
    k_final<<<gG, 256, 0, stream>>>(bufA, W2, b2, out, N);
}

// Round 7
// 650.584 us; speedup vs baseline: 1.2486x; 1.2486x over previous
//
#include <hip/hip_runtime.h>

// ---------------------------------------------------------------------------
// GCN forward:  relu(x@W1+b1) -> gcnconv(Wc1) -> relu -> gcnconv(Wc2) -> relu
//               -> @W2 + b2
//
// R7: build reverted to R3's per-node CSR (100k distributed counters; R6's
//     1563-hot-counter bhist hit same-address atomic serialization: 237 µs,
//     ~230 ns/op cross-XCD line ping-pong. Distributed >> concentrated).
//     gemm1 keeps R6's 256x64 tile / 8x8 microtile, restructured to lower
//     register pressure (b-frags loaded per-qq; live ~104 VGPR).
//     bf16 t' path unchanged (absmax 9.77e-4).
// ---------------------------------------------------------------------------

__device__ __forceinline__ unsigned bf16_rne(float f) {
    unsigned u = __float_as_uint(f);
    return (u + 0x7fffu + ((u >> 16) & 1u)) >> 16;   // finite inputs only
}

__device__ __forceinline__ void unpack8(uint4 p, float v[8]) {
    v[0] = __uint_as_float(p.x << 16); v[1] = __uint_as_float(p.x & 0xffff0000u);
    v[2] = __uint_as_float(p.y << 16); v[3] = __uint_as_float(p.y & 0xffff0000u);
    v[4] = __uint_as_float(p.z << 16); v[5] = __uint_as_float(p.z & 0xffff0000u);
    v[6] = __uint_as_float(p.w << 16); v[7] = __uint_as_float(p.w & 0xffff0000u);
}

// ============================= CSR build (per-node, distributed) ===========

__global__ __launch_bounds__(256) void k_zero_cnt(int* __restrict__ cnt, int n) {
    int i = blockIdx.x * 256 + threadIdx.x;
    if (i < n) cnt[i] = 0;
}

__global__ __launch_bounds__(256) void k_hist(const int* __restrict__ col,
                                              int* __restrict__ cnt,
                                              int* __restrict__ rank, int ne) {
    int i = blockIdx.x * 256 + threadIdx.x;
    if (i < ne) rank[i] = atomicAdd(&cnt[col[i]], 1);
}

__global__ __launch_bounds__(256) void k_scan1(const int* __restrict__ cnt,
                                               int* __restrict__ ptr,
                                               int* __restrict__ bsum, int n) {
    __shared__ int s[256];
    const int t = threadIdx.x;
    const int i = blockIdx.x * 256 + t;
    int v = (i < n) ? cnt[i] : 0;
    s[t] = v;
    __syncthreads();
#pragma unroll
    for (int off = 1; off < 256; off <<= 1) {
        int x = (t >= off) ? s[t - off] : 0;
        __syncthreads();
        s[t] += x;
        __syncthreads();
    }
    if (i < n) ptr[i] = s[t] - v;
    if (t == 255) bsum[blockIdx.x] = s[255];
}

__global__ __launch_bounds__(512) void k_scan2(int* __restrict__ bsum, int nb) {
    __shared__ int s[512];
    const int t = threadIdx.x;
    int v = (t < nb) ? bsum[t] : 0;
    s[t] = v;
    __syncthreads();
#pragma unroll
    for (int off = 1; off < 512; off <<= 1) {
        int x = (t >= off) ? s[t - off] : 0;
        __syncthreads();
        s[t] += x;
        __syncthreads();
    }
    if (t < nb) bsum[t] = s[t] - v;
}

__global__ __launch_bounds__(256) void k_scan3(int* __restrict__ ptr,
                                               const int* __restrict__ bsum,
                                               int n, int etot) {
    int i = blockIdx.x * 256 + threadIdx.x;
    if (i < n) ptr[i] = ptr[i] + bsum[i >> 8];
    if (i == 0) ptr[n] = etot;
}

__global__ __launch_bounds__(256) void k_scatter(const int* __restrict__ row,
                                                 const int* __restrict__ col,
                                                 const float* __restrict__ ew,
                                                 const int* __restrict__ ptr,
                                                 const int* __restrict__ rank,
                                                 int2* __restrict__ recs, int ne) {
    int i = blockIdx.x * 256 + threadIdx.x;
    if (i < ne) {
        int c = col[i];
        int pos = ptr[c] + rank[i];
        recs[pos] = make_int2(row[i], __float_as_int(ew[i]));
    }
}

__global__ __launch_bounds__(256) void k_csr_deg(const int* __restrict__ ptr,
                                                 const int2* __restrict__ recs,
                                                 float* __restrict__ dinv, int n) {
    int i = blockIdx.x * 256 + threadIdx.x;
    if (i < n) {
        int s = ptr[i], e = ptr[i + 1];
        float d = 1.0f;  // self-loop
        for (int j = s; j < e; ++j) d += __int_as_float(recs[j].y);
        dinv[i] = rsqrtf(d);
    }
}

// ============================= GEMM1 =======================================
// h = relu(x @ W1 + b1); x[N,256], W1[256,64].
// 256x64 tile, 8x8 microtile (tx=tid&7 -> cols tx*8..+7; rows j*32+ty).
// b-fragments loaded inside the qq loop: live regs ~= 64 acc + 32 a + 8 b.
__global__ __launch_bounds__(256) void k_gemm1(const float* __restrict__ x,
                                               const float* __restrict__ W,
                                               const float* __restrict__ bias,
                                               float* __restrict__ h, int n) {
    __shared__ float xs[256 * 36];   // 36 KB
    __shared__ float ws[32 * 64];    // 8 KB
    const int tid = threadIdx.x;
    const int row0 = blockIdx.x * 256;
    const int tx = tid & 7;
    const int ty = tid >> 3;
    float acc[8][8] = {};

    for (int kb = 0; kb < 8; ++kb) {
        const int k0 = kb * 32;
#pragma unroll
        for (int i = 0; i < 2; ++i) {           // W chunk 32x64
            int f = tid + i * 256;
            int kr = f >> 4, cc = (f & 15) * 4;
            *(float4*)(ws + kr * 64 + cc) =
                *(const float4*)(W + (size_t)(k0 + kr) * 64 + cc);
        }
#pragma unroll
        for (int i = 0; i < 8; ++i) {           // x tile 256x32
            int f = tid + i * 256;
            int r = f >> 3, kc = (f & 7) * 4;
            int row = row0 + r;
            float4 v = make_float4(0.f, 0.f, 0.f, 0.f);
            if (row < n) v = *(const float4*)(x + (size_t)row * 256 + k0 + kc);
            *(float4*)(xs + r * 36 + kc) = v;
        }
        __syncthreads();
#pragma unroll
        for (int kk = 0; kk < 32; kk += 4) {
            float a[8][4];
#pragma unroll
            for (int j = 0; j < 8; ++j) {
                float4 av = *(const float4*)(xs + (j * 32 + ty) * 36 + kk);
                a[j][0] = av.x; a[j][1] = av.y; a[j][2] = av.z; a[j][3] = av.w;
            }
#pragma unroll
            for (int qq = 0; qq < 4; ++qq) {
                float4 b0 = *(const float4*)(ws + (kk + qq) * 64 + tx * 8);
                float4 b1 = *(const float4*)(ws + (kk + qq) * 64 + tx * 8 + 4);
#pragma unroll
                for (int j = 0; j < 8; ++j) {
                    acc[j][0] = fmaf(a[j][qq], b0.x, acc[j][0]);
                    acc[j][1] = fmaf(a[j][qq], b0.y, acc[j][1]);
                    acc[j][2] = fmaf(a[j][qq], b0.z, acc[j][2]);
                    acc[j][3] = fmaf(a[j][qq], b0.w, acc[j][3]);
                    acc[j][4] = fmaf(a[j][qq], b1.x, acc[j][4]);
                    acc[j][5] = fmaf(a[j][qq], b1.y, acc[j][5]);
                    acc[j][6] = fmaf(a[j][qq], b1.z, acc[j][6]);
                    acc[j][7] = fmaf(a[j][qq], b1.w, acc[j][7]);
                }
            }
        }
        __syncthreads();
    }

    float4 bb0 = *(const float4*)(bias + tx * 8);
    float4 bb1 = *(const float4*)(bias + tx * 8 + 4);
#pragma unroll
    for (int j = 0; j < 8; ++j) {
        int row = row0 + j * 32 + ty;
        if (row < n) {
            float4 o0, o1;
            o0.x = fmaxf(acc[j][0] + bb0.x, 0.f);
            o0.y = fmaxf(acc[j][1] + bb0.y, 0.f);
            o0.z = fmaxf(acc[j][2] + bb0.z, 0.f);
            o0.w = fmaxf(acc[j][3] + bb0.w, 0.f);
            o1.x = fmaxf(acc[j][4] + bb1.x, 0.f);
            o1.y = fmaxf(acc[j][5] + bb1.y, 0.f);
            o1.z = fmaxf(acc[j][6] + bb1.z, 0.f);
            o1.w = fmaxf(acc[j][7] + bb1.w, 0.f);
            *(float4*)(h + (size_t)row * 64 + tx * 8) = o0;
            *(float4*)(h + (size_t)row * 64 + tx * 8 + 4) = o1;
        }
    }
}

// ============================= Conv dense part =============================
// t'[r] = bf16( dinv[r] * (hin @ W)[r] )   -- bf16, 128 B per row
__global__ __launch_bounds__(256) void k_conv(const float* __restrict__ hin,
                                              const float* __restrict__ W,
                                              const float* __restrict__ dinv,
                                              unsigned* __restrict__ tb,
                                              int n) {
    __shared__ float xs[64 * 68];
    __shared__ float ws[64 * 64];
    const int tid = threadIdx.x;
    const int row0 = blockIdx.x * 64;
    const int tx = tid & 15, ty = tid >> 4;

    {
        const float4* src = (const float4*)W;
        float4* dst = (float4*)ws;
#pragma unroll
        for (int i = 0; i < 4; ++i) dst[tid + i * 256] = src[tid + i * 256];
    }
#pragma unroll
    for (int i = 0; i < 4; ++i) {
        int f = tid + i * 256;
        int r = f >> 4;
        int c = (f & 15) * 4;
        int row = row0 + r;
        float4 v = make_float4(0.f, 0.f, 0.f, 0.f);
        if (row < n) v = *(const float4*)(hin + (size_t)row * 64 + c);
        *(float4*)(xs + r * 68 + c) = v;
    }
    __syncthreads();

    float acc[4][4] = {};
#pragma unroll
    for (int kk = 0; kk < 64; kk += 4) {
        float4 a[4], b[4];
#pragma unroll
        for (int j = 0; j < 4; ++j)
            a[j] = *(const float4*)(xs + (ty * 4 + j) * 68 + kk);
#pragma unroll
        for (int qq = 0; qq < 4; ++qq)
            b[qq] = *(const float4*)(ws + (kk + qq) * 64 + tx * 4);
#pragma unroll
        for (int j = 0; j < 4; ++j) {
            float aj[4] = {a[j].x, a[j].y, a[j].z, a[j].w};
#pragma unroll
            for (int qq = 0; qq < 4; ++qq) {
                acc[j][0] = fmaf(aj[qq], b[qq].x, acc[j][0]);
                acc[j][1] = fmaf(aj[qq], b[qq].y, acc[j][1]);
                acc[j][2] = fmaf(aj[qq], b[qq].z, acc[j][2]);
                acc[j][3] = fmaf(aj[qq], b[qq].w, acc[j][3]);
            }
        }
    }
#pragma unroll
    for (int j = 0; j < 4; ++j) {
        int row = row0 + ty * 4 + j;
        if (row < n) {
            float dv = dinv[row];
            uint2 w;
            w.x = bf16_rne(dv * acc[j][0]) | (bf16_rne(dv * acc[j][1]) << 16);
            w.y = bf16_rne(dv * acc[j][2]) | (bf16_rne(dv * acc[j][3]) << 16);
            *(uint2*)(tb + (size_t)row * 32 + tx * 2) = w;
        }
    }
}

// ============================= CSR aggregation =============================
__global__ __launch_bounds__(256) void k_agg(const int* __restrict__ ptr,
                                             const int2* __restrict__ recs,
                                             const float* __restrict__ dinv,
                                             const float* __restrict__ bias,
                                             const uint4* __restrict__ t4,
                                             float4* __restrict__ agg4, int n) {
    const int lane = threadIdx.x & 63;
    const int c = blockIdx.x * 4 + (threadIdx.x >> 6);
    if (c >= n) return;
    const int grp = lane >> 3;
    const int f = lane & 7;

    float acc[8] = {};
    if (grp == 0) {
        float v[8];
        unpack8(t4[(size_t)c * 8 + f], v);
#pragma unroll
        for (int i = 0; i < 8; ++i) acc[i] = v[i];
    }

    const int eEnd = ptr[c + 1];
    int e = ptr[c] + grp;
    int2 rec = (e < eEnd) ? recs[e] : make_int2(0, 0);
    while (e < eEnd) {
        int2 cur = rec;
        e += 8;
        if (e < eEnd) rec = recs[e];
        uint4 p = t4[(size_t)cur.x * 8 + f];
        float w = __int_as_float(cur.y);
        float v[8];
        unpack8(p, v);
#pragma unroll
        for (int i = 0; i < 8; ++i) acc[i] = fmaf(w, v[i], acc[i]);
    }

#pragma unroll
    for (int off = 8; off < 64; off <<= 1) {
#pragma unroll
        for (int i = 0; i < 8; ++i) acc[i] += __shfl_xor(acc[i], off, 64);
    }

    if (grp == 0) {
        const float wc = dinv[c];
        float4 b0 = ((const float4*)bias)[f * 2];
        float4 b1 = ((const float4*)bias)[f * 2 + 1];
        float4 o0, o1;
        o0.x = fmaxf(fmaf(wc, acc[0], b0.x), 0.f);
        o0.y = fmaxf(fmaf(wc, acc[1], b0.y), 0.f);
        o0.z = fmaxf(fmaf(wc, acc[2], b0.z), 0.f);
        o0.w = fmaxf(fmaf(wc, acc[3], b0.w), 0.f);
        o1.x = fmaxf(fmaf(wc, acc[4], b1.x), 0.f);
        o1.y = fmaxf(fmaf(wc, acc[5], b1.y), 0.f);
        o1.z = fmaxf(fmaf(wc, acc[6], b1.z), 0.f);
        o1.w = fmaxf(fmaf(wc, acc[7], b1.w), 0.f);
        agg4[(size_t)c * 16 + f * 2] = o0;
        agg4[(size_t)c * 16 + f * 2 + 1] = o1;
    }
}

// ============================= Final GEMM ==================================
__global__ __launch_bounds__(256) void k_final(const float* __restrict__ hin,
                                               const float* __restrict__ W,
                                               const float* __restrict__ bias,
                                               float* __restrict__ out, int n) {
    __shared__ float xs[64 * 68];
    __shared__ float ws[64 * 40];
    const int tid = threadIdx.x;
    const int row0 = blockIdx.x * 64;

    for (int i = tid; i < 640; i += 256)
        ((float4*)ws)[i] = ((const float4*)W)[i];
#pragma unroll
    for (int i = 0; i < 4; ++i) {
        int f = tid + i * 256;
        int r = f >> 4;
        int c = (f & 15) * 4;
        int row = row0 + r;
        float4 v = make_float4(0.f, 0.f, 0.f, 0.f);
        if (row < n) v = *(const float4*)(hin + (size_t)row * 64 + c);
        *(float4*)(xs + r * 68 + c) = v;
    }
    __syncthreads();

    const int tx = tid & 15, ty = tid >> 4;
    if (tx < 10) {
        float acc[4][4] = {};
#pragma unroll
        for (int kk = 0; kk < 64; kk += 4) {
            float4 a[4], b[4];
#pragma unroll
            for (int j = 0; j < 4; ++j)
                a[j] = *(const float4*)(xs + (ty * 4 + j) * 68 + kk);
#pragma unroll
            for (int qq = 0; qq < 4; ++qq)
                b[qq] = *(const float4*)(ws + (kk + qq) * 40 + tx * 4);
#pragma unroll
            for (int j = 0; j < 4; ++j) {
                float aj[4] = {a[j].x, a[j].y, a[j].z, a[j].w};
#pragma unroll
                for (int qq = 0; qq < 4; ++qq) {
                    acc[j][0] = fmaf(aj[qq], b[qq].x, acc[j][0]);
                    acc[j][1] = fmaf(aj[qq], b[qq].y, acc[j][1]);
                    acc[j][2] = fmaf(aj[qq], b[qq].z, acc[j][2]);
                    acc[j][3] = fmaf(aj[qq], b[qq].w, acc[j][3]);
                }
            }
        }
        float4 bb = *(const float4*)(bias + tx * 4);
#pragma unroll
        for (int j = 0; j < 4; ++j) {
            int row = row0 + ty * 4 + j;
            if (row < n) {
                float4 o = make_float4(acc[j][0] + bb.x, acc[j][1] + bb.y,
                                       acc[j][2] + bb.z, acc[j][3] + bb.w);
                *(float4*)(out + (size_t)row * 40 + tx * 4) = o;
            }
        }
    }
}

extern "C" void kernel_launch(void* const* d_in, const int* in_sizes, int n_in,
                              void* d_out, int out_size, void* d_ws, size_t ws_size,
                              hipStream_t stream) {
    const float* x   = (const float*)d_in[0];
    const int*   ei  = (const int*)d_in[1];
    const float* ew  = (const float*)d_in[2];
    const float* W1  = (const float*)d_in[3];
    const float* b1  = (const float*)d_in[4];
    const float* Wc1 = (const float*)d_in[5];
    const float* bc1 = (const float*)d_in[6];
    const float* Wc2 = (const float*)d_in[7];
    const float* bc2 = (const float*)d_in[8];
    const float* W2  = (const float*)d_in[9];
    const float* b2  = (const float*)d_in[10];
    float* out = (float*)d_out;

    const int N = in_sizes[0] / 256;
    const int E = in_sizes[2];
    const int* row = ei;
    const int* col = ei + E;

    // workspace layout:
    // recs[E int2] | bufA[64N f] | bufB[64N f] | dinv[N f] | cnt[N i]
    //   | ptr[N+1 i] | bsum[512 i]
    // rank[E] aliases head of bufA (dead after k_scatter, before k_gemm1).
    // bufB doubles as bf16 t' (first 32N floats).
    int2*  recs = (int2*)d_ws;
    float* bufA = (float*)(recs + E);
    float* bufB = bufA + (size_t)N * 64;
    float* dinv = bufB + (size_t)N * 64;
    int*   cnt  = (int*)(dinv + N);
    int*   ptr  = cnt + N;
    int*   bsum = ptr + N + 1;
    int*   rank = (int*)bufA;
    unsigned* tb = (unsigned*)bufB;

    const int gN = (N + 255) / 256;
    const int gE = (E + 255) / 256;
    const int gG = (N + 63) / 64;
    const int gA = (N + 3) / 4;
    const int gG1 = (N + 255) / 256;

    // --- per-node CSR build (distributed atomics; shared by both convs) ---
    k_zero_cnt<<<gN, 256, 0, stream>>>(cnt, N);
    k_hist<<<gE, 256, 0, stream>>>(col, cnt, rank, E);
    k_scan1<<<gN, 256, 0, stream>>>(cnt, ptr, bsum, N);
    k_scan2<<<1, 512, 0, stream>>>(bsum, gN);
    k_scan3<<<gN, 256, 0, stream>>>(ptr, bsum, N, E);
    k_scatter<<<gE, 256, 0, stream>>>(row, col, ew, ptr, rank, recs, E);
    k_csr_deg<<<gN, 256, 0, stream>>>(ptr, recs, dinv, N);

    // --- layer 1: h1 = relu(x@W1+b1) -> bufA ---
    k_gemm1<<<gG1, 256, 0, stream>>>(x, W1, b1, bufA, N);

    // --- conv1 ---
    k_conv<<<gG, 256, 0, stream>>>(bufA, Wc1, dinv, tb, N);
    k_agg<<<gA, 256, 0, stream>>>(ptr, recs, dinv, bc1, (const uint4*)tb,
                                  (float4*)bufA, N);

    // --- conv2 ---
    k_conv<<<gG, 256, 0, stream>>>(bufA, Wc2, dinv, tb, N);
    k_agg<<<gA, 256, 0, stream>>>(ptr, recs, dinv, bc2, (const uint4*)tb,
                                  (float4*)bufA, N);

    // --- out = agg2 @ W2 + b2 ---
    k_final<<<gG, 256, 0, stream>>>(bufA, W2, b2, out, N);
}

// Round 8
// 547.408 us; speedup vs baseline: 1.4839x; 1.1885x over previous
//
#include <hip/hip_runtime.h>

// ---------------------------------------------------------------------------
// GCN forward:  relu(x@W1+b1) -> gcnconv(Wc1) -> relu -> gcnconv(Wc2) -> relu
//               -> @W2 + b2
//
// R8: (a) gemm1 = 128x64 tile, 8x4 microtile, BK=32 (R7's 256x64/8x8 had
//         391 blocks -> 8.7% occupancy, latency-bound at 163 us).
//     (b) hist and gemm1 are independent -> fused into ONE kernel (gemm
//         blocks first, hist blocks after): atomic-latency waves co-schedule
//         with VALU/LDS waves (m114: separate pipes overlap).
//         rank[] moved to dedicated ws (no longer aliases bufA).
//     (c) scan2+scan3 merged (each block prefix-reduces bsum from L2).
//     bf16 t' prefold path unchanged (absmax 9.77e-4).
// ---------------------------------------------------------------------------

__device__ __forceinline__ unsigned bf16_rne(float f) {
    unsigned u = __float_as_uint(f);
    return (u + 0x7fffu + ((u >> 16) & 1u)) >> 16;   // finite inputs only
}

__device__ __forceinline__ void unpack8(uint4 p, float v[8]) {
    v[0] = __uint_as_float(p.x << 16); v[1] = __uint_as_float(p.x & 0xffff0000u);
    v[2] = __uint_as_float(p.y << 16); v[3] = __uint_as_float(p.y & 0xffff0000u);
    v[4] = __uint_as_float(p.z << 16); v[5] = __uint_as_float(p.z & 0xffff0000u);
    v[6] = __uint_as_float(p.w << 16); v[7] = __uint_as_float(p.w & 0xffff0000u);
}

// ============================= small build kernels =========================

__global__ __launch_bounds__(256) void k_zero_cnt(int* __restrict__ cnt, int n) {
    int i = blockIdx.x * 256 + threadIdx.x;
    if (i < n) cnt[i] = 0;
}

__global__ __launch_bounds__(256) void k_scan1(const int* __restrict__ cnt,
                                               int* __restrict__ ptr,
                                               int* __restrict__ bsum, int n) {
    __shared__ int s[256];
    const int t = threadIdx.x;
    const int i = blockIdx.x * 256 + t;
    int v = (i < n) ? cnt[i] : 0;
    s[t] = v;
    __syncthreads();
#pragma unroll
    for (int off = 1; off < 256; off <<= 1) {
        int x = (t >= off) ? s[t - off] : 0;
        __syncthreads();
        s[t] += x;
        __syncthreads();
    }
    if (i < n) ptr[i] = s[t] - v;
    if (t == 255) bsum[blockIdx.x] = s[255];
}

// block b adds sum(bsum[0..b-1]) to its 256 ptr entries (bsum is L2-hot)
__global__ __launch_bounds__(256) void k_scan23(int* __restrict__ ptr,
                                                const int* __restrict__ bsum,
                                                int n, int etot) {
    __shared__ int s[256];
    const int t = threadIdx.x;
    const int b = blockIdx.x;
    int partial = 0;
    for (int j = t; j < b; j += 256) partial += bsum[j];
    s[t] = partial;
    __syncthreads();
#pragma unroll
    for (int off = 128; off > 0; off >>= 1) {
        if (t < off) s[t] += s[t + off];
        __syncthreads();
    }
    const int add = s[0];
    int i = b * 256 + t;
    if (i < n) ptr[i] += add;
    if (b == 0 && t == 0) ptr[n] = etot;
}

__global__ __launch_bounds__(256) void k_scatter(const int* __restrict__ row,
                                                 const int* __restrict__ col,
                                                 const float* __restrict__ ew,
                                                 const int* __restrict__ ptr,
                                                 const int* __restrict__ rank,
                                                 int2* __restrict__ recs, int ne) {
    int i = blockIdx.x * 256 + threadIdx.x;
    if (i < ne) {
        int c = col[i];
        int pos = ptr[c] + rank[i];
        recs[pos] = make_int2(row[i], __float_as_int(ew[i]));
    }
}

__global__ __launch_bounds__(256) void k_csr_deg(const int* __restrict__ ptr,
                                                 const int2* __restrict__ recs,
                                                 float* __restrict__ dinv, int n) {
    int i = blockIdx.x * 256 + threadIdx.x;
    if (i < n) {
        int s = ptr[i], e = ptr[i + 1];
        float d = 1.0f;  // self-loop
        for (int j = s; j < e; ++j) d += __int_as_float(recs[j].y);
        dinv[i] = rsqrtf(d);
    }
}

// ============================= fused hist + GEMM1 ==========================
// blocks [0, gemmBlocks): h = relu(x@W1+b1), 128x64 tile, 8x4 microtile.
// blocks [gemmBlocks, ...): rank[e] = atomicAdd(&cnt[col[e]], 1).
// Independent work; hist waves are atomic-latency-bound (no VALU/LDS use),
// so they co-schedule with the gemm waves instead of serializing after them.
__global__ __launch_bounds__(256) void k_fused1(const float* __restrict__ x,
                                                const float* __restrict__ W,
                                                const float* __restrict__ bias,
                                                float* __restrict__ h, int n,
                                                const int* __restrict__ col,
                                                int* __restrict__ cnt,
                                                int* __restrict__ rank, int ne,
                                                int gemmBlocks) {
    if (blockIdx.x >= gemmBlocks) {
        int i = (blockIdx.x - gemmBlocks) * 256 + threadIdx.x;
        if (i < ne) rank[i] = atomicAdd(&cnt[col[i]], 1);
        return;
    }

    __shared__ float xs[128 * 36];   // 18.4 KB, stride 36 (bank-spread)
    __shared__ float ws[32 * 64];    // 8 KB
    const int tid = threadIdx.x;
    const int row0 = blockIdx.x * 128;
    const int tx = tid & 15;         // cols tx*4 .. +3
    const int ty = tid >> 4;         // rows j*16 + ty
    float acc[8][4] = {};

    for (int kb = 0; kb < 8; ++kb) {
        const int k0 = kb * 32;
#pragma unroll
        for (int i = 0; i < 2; ++i) {            // W chunk 32x64
            int f = tid + i * 256;
            int kr = f >> 4, cc = (f & 15) * 4;
            *(float4*)(ws + kr * 64 + cc) =
                *(const float4*)(W + (size_t)(k0 + kr) * 64 + cc);
        }
#pragma unroll
        for (int i = 0; i < 4; ++i) {            // x tile 128x32
            int f = tid + i * 256;
            int r = f >> 3, kc = (f & 7) * 4;
            int row = row0 + r;
            float4 v = make_float4(0.f, 0.f, 0.f, 0.f);
            if (row < n) v = *(const float4*)(x + (size_t)row * 256 + k0 + kc);
            *(float4*)(xs + r * 36 + kc) = v;
        }
        __syncthreads();
#pragma unroll
        for (int kk = 0; kk < 32; kk += 4) {
            float a[8][4];
#pragma unroll
            for (int j = 0; j < 8; ++j) {
                float4 av = *(const float4*)(xs + (j * 16 + ty) * 36 + kk);
                a[j][0] = av.x; a[j][1] = av.y; a[j][2] = av.z; a[j][3] = av.w;
            }
#pragma unroll
            for (int qq = 0; qq < 4; ++qq) {
                float4 b = *(const float4*)(ws + (kk + qq) * 64 + tx * 4);
#pragma unroll
                for (int j = 0; j < 8; ++j) {
                    acc[j][0] = fmaf(a[j][qq], b.x, acc[j][0]);
                    acc[j][1] = fmaf(a[j][qq], b.y, acc[j][1]);
                    acc[j][2] = fmaf(a[j][qq], b.z, acc[j][2]);
                    acc[j][3] = fmaf(a[j][qq], b.w, acc[j][3]);
                }
            }
        }
        __syncthreads();
    }

    float4 bb = *(const float4*)(bias + tx * 4);
#pragma unroll
    for (int j = 0; j < 8; ++j) {
        int row = row0 + j * 16 + ty;
        if (row < n) {
            float4 o;
            o.x = fmaxf(acc[j][0] + bb.x, 0.f);
            o.y = fmaxf(acc[j][1] + bb.y, 0.f);
            o.z = fmaxf(acc[j][2] + bb.z, 0.f);
            o.w = fmaxf(acc[j][3] + bb.w, 0.f);
            *(float4*)(h + (size_t)row * 64 + tx * 4) = o;
        }
    }
}

// ============================= Conv dense part =============================
// t'[r] = bf16( dinv[r] * (hin @ W)[r] )   -- bf16, 128 B per row
__global__ __launch_bounds__(256) void k_conv(const float* __restrict__ hin,
                                              const float* __restrict__ W,
                                              const float* __restrict__ dinv,
                                              unsigned* __restrict__ tb,
                                              int n) {
    __shared__ float xs[64 * 68];
    __shared__ float ws[64 * 64];
    const int tid = threadIdx.x;
    const int row0 = blockIdx.x * 64;
    const int tx = tid & 15, ty = tid >> 4;

    {
        const float4* src = (const float4*)W;
        float4* dst = (float4*)ws;
#pragma unroll
        for (int i = 0; i < 4; ++i) dst[tid + i * 256] = src[tid + i * 256];
    }
#pragma unroll
    for (int i = 0; i < 4; ++i) {
        int f = tid + i * 256;
        int r = f >> 4;
        int c = (f & 15) * 4;
        int row = row0 + r;
        float4 v = make_float4(0.f, 0.f, 0.f, 0.f);
        if (row < n) v = *(const float4*)(hin + (size_t)row * 64 + c);
        *(float4*)(xs + r * 68 + c) = v;
    }
    __syncthreads();

    float acc[4][4] = {};
#pragma unroll
    for (int kk = 0; kk < 64; kk += 4) {
        float4 a[4], b[4];
#pragma unroll
        for (int j = 0; j < 4; ++j)
            a[j] = *(const float4*)(xs + (ty * 4 + j) * 68 + kk);
#pragma unroll
        for (int qq = 0; qq < 4; ++qq)
            b[qq] = *(const float4*)(ws + (kk + qq) * 64 + tx * 4);
#pragma unroll
        for (int j = 0; j < 4; ++j) {
            float aj[4] = {a[j].x, a[j].y, a[j].z, a[j].w};
#pragma unroll
            for (int qq = 0; qq < 4; ++qq) {
                acc[j][0] = fmaf(aj[qq], b[qq].x, acc[j][0]);
                acc[j][1] = fmaf(aj[qq], b[qq].y, acc[j][1]);
                acc[j][2] = fmaf(aj[qq], b[qq].z, acc[j][2]);
                acc[j][3] = fmaf(aj[qq], b[qq].w, acc[j][3]);
            }
        }
    }
#pragma unroll
    for (int j = 0; j < 4; ++j) {
        int row = row0 + ty * 4 + j;
        if (row < n) {
            float dv = dinv[row];
            uint2 w;
            w.x = bf16_rne(dv * acc[j][0]) | (bf16_rne(dv * acc[j][1]) << 16);
            w.y = bf16_rne(dv * acc[j][2]) | (bf16_rne(dv * acc[j][3]) << 16);
            *(uint2*)(tb + (size_t)row * 32 + tx * 2) = w;
        }
    }
}

// ============================= CSR aggregation =============================
__global__ __launch_bounds__(256) void k_agg(const int* __restrict__ ptr,
                                             const int2* __restrict__ recs,
                                             const float* __restrict__ dinv,
                                             const float* __restrict__ bias,
                                             const uint4* __restrict__ t4,
                                             float4* __restrict__ agg4, int n) {
    const int lane = threadIdx.x & 63;
    const int c = blockIdx.x * 4 + (threadIdx.x >> 6);
    if (c >= n) return;
    const int grp = lane >> 3;
    const int f = lane & 7;

    float acc[8] = {};
    if (grp == 0) {
        float v[8];
        unpack8(t4[(size_t)c * 8 + f], v);
#pragma unroll
        for (int i = 0; i < 8; ++i) acc[i] = v[i];
    }

    const int eEnd = ptr[c + 1];
    int e = ptr[c] + grp;
    int2 rec = (e < eEnd) ? recs[e] : make_int2(0, 0);
    while (e < eEnd) {
        int2 cur = rec;
        e += 8;
        if (e < eEnd) rec = recs[e];
        uint4 p = t4[(size_t)cur.x * 8 + f];
        float w = __int_as_float(cur.y);
        float v[8];
        unpack8(p, v);
#pragma unroll
        for (int i = 0; i < 8; ++i) acc[i] = fmaf(w, v[i], acc[i]);
    }

#pragma unroll
    for (int off = 8; off < 64; off <<= 1) {
#pragma unroll
        for (int i = 0; i < 8; ++i) acc[i] += __shfl_xor(acc[i], off, 64);
    }

    if (grp == 0) {
        const float wc = dinv[c];
        float4 b0 = ((const float4*)bias)[f * 2];
        float4 b1 = ((const float4*)bias)[f * 2 + 1];
        float4 o0, o1;
        o0.x = fmaxf(fmaf(wc, acc[0], b0.x), 0.f);
        o0.y = fmaxf(fmaf(wc, acc[1], b0.y), 0.f);
        o0.z = fmaxf(fmaf(wc, acc[2], b0.z), 0.f);
        o0.w = fmaxf(fmaf(wc, acc[3], b0.w), 0.f);
        o1.x = fmaxf(fmaf(wc, acc[4], b1.x), 0.f);
        o1.y = fmaxf(fmaf(wc, acc[5], b1.y), 0.f);
        o1.z = fmaxf(fmaf(wc, acc[6], b1.z), 0.f);
        o1.w = fmaxf(fmaf(wc, acc[7], b1.w), 0.f);
        agg4[(size_t)c * 16 + f * 2] = o0;
        agg4[(size_t)c * 16 + f * 2 + 1] = o1;
    }
}

// ============================= Final GEMM ==================================
__global__ __launch_bounds__(256) void k_final(const float* __restrict__ hin,
                                               const float* __restrict__ W,
                                               const float* __restrict__ bias,
                                               float* __restrict__ out, int n) {
    __shared__ float xs[64 * 68];
    __shared__ float ws[64 * 40];
    const int tid = threadIdx.x;
    const int row0 = blockIdx.x * 64;

    for (int i = tid; i < 640; i += 256)
        ((float4*)ws)[i] = ((const float4*)W)[i];
#pragma unroll
    for (int i = 0; i < 4; ++i) {
        int f = tid + i * 256;
        int r = f >> 4;
        int c = (f & 15) * 4;
        int row = row0 + r;
        float4 v = make_float4(0.f, 0.f, 0.f, 0.f);
        if (row < n) v = *(const float4*)(hin + (size_t)row * 64 + c);
        *(float4*)(xs + r * 68 + c) = v;
    }
    __syncthreads();

    const int tx = tid & 15, ty = tid >> 4;
    if (tx < 10) {
        float acc[4][4] = {};
#pragma unroll
        for (int kk = 0; kk < 64; kk += 4) {
            float4 a[4], b[4];
#pragma unroll
            for (int j = 0; j < 4; ++j)
                a[j] = *(const float4*)(xs + (ty * 4 + j) * 68 + kk);
#pragma unroll
            for (int qq = 0; qq < 4; ++qq)
                b[qq] = *(const float4*)(ws + (kk + qq) * 40 + tx * 4);
#pragma unroll
            for (int j = 0; j < 4; ++j) {
                float aj[4] = {a[j].x, a[j].y, a[j].z, a[j].w};
#pragma unroll
                for (int qq = 0; qq < 4; ++qq) {
                    acc[j][0] = fmaf(aj[qq], b[qq].x, acc[j][0]);
                    acc[j][1] = fmaf(aj[qq], b[qq].y, acc[j][1]);
                    acc[j][2] = fmaf(aj[qq], b[qq].z, acc[j][2]);
                    acc[j][3] = fmaf(aj[qq], b[qq].w, acc[j][3]);
                }
            }
        }
        float4 bb = *(const float4*)(bias + tx * 4);
#pragma unroll
        for (int j = 0; j < 4; ++j) {
            int row = row0 + ty * 4 + j;
            if (row < n) {
                float4 o = make_float4(acc[j][0] + bb.x, acc[j][1] + bb.y,
                                       acc[j][2] + bb.z, acc[j][3] + bb.w);
                *(float4*)(out + (size_t)row * 40 + tx * 4) = o;
            }
        }
    }
}

extern "C" void kernel_launch(void* const* d_in, const int* in_sizes, int n_in,
                              void* d_out, int out_size, void* d_ws, size_t ws_size,
                              hipStream_t stream) {
    const float* x   = (const float*)d_in[0];
    const int*   ei  = (const int*)d_in[1];
    const float* ew  = (const float*)d_in[2];
    const float* W1  = (const float*)d_in[3];
    const float* b1  = (const float*)d_in[4];
    const float* Wc1 = (const float*)d_in[5];
    const float* bc1 = (const float*)d_in[6];
    const float* Wc2 = (const float*)d_in[7];
    const float* bc2 = (const float*)d_in[8];
    const float* W2  = (const float*)d_in[9];
    const float* b2  = (const float*)d_in[10];
    float* out = (float*)d_out;

    const int N = in_sizes[0] / 256;
    const int E = in_sizes[2];
    const int* row = ei;
    const int* col = ei + E;

    // workspace layout:
    // recs[E int2] | bufA[64N f] | bufB[64N f] | dinv[N f] | cnt[N i]
    //   | ptr[N+1 i] | bsum[512 i] | rank[E i]
    // rank has its OWN region now (hist runs concurrently with gemm1 which
    // writes bufA). bufB doubles as bf16 t' (first 32N floats).
    int2*  recs = (int2*)d_ws;
    float* bufA = (float*)(recs + E);
    float* bufB = bufA + (size_t)N * 64;
    float* dinv = bufB + (size_t)N * 64;
    int*   cnt  = (int*)(dinv + N);
    int*   ptr  = cnt + N;
    int*   bsum = ptr + N + 1;
    int*   rank = bsum + 512;
    unsigned* tb = (unsigned*)bufB;

    const int gN = (N + 255) / 256;       // 391
    const int gE = (E + 255) / 256;       // 6250
    const int gG = (N + 63) / 64;         // 1563
    const int gA = (N + 3) / 4;           // 25000
    const int gB = (N + 127) / 128;       // 782 gemm blocks

    // --- zero counters, then fused [gemm1 || hist] ---
    k_zero_cnt<<<gN, 256, 0, stream>>>(cnt, N);
    k_fused1<<<gB + gE, 256, 0, stream>>>(x, W1, b1, bufA, N,
                                          col, cnt, rank, E, gB);

    // --- finish CSR build ---
    k_scan1<<<gN, 256, 0, stream>>>(cnt, ptr, bsum, N);
    k_scan23<<<gN, 256, 0, stream>>>(ptr, bsum, N, E);
    k_scatter<<<gE, 256, 0, stream>>>(row, col, ew, ptr, rank, recs, E);
    k_csr_deg<<<gN, 256, 0, stream>>>(ptr, recs, dinv, N);

    // --- conv1 ---
    k_conv<<<gG, 256, 0, stream>>>(bufA, Wc1, dinv, tb, N);
    k_agg<<<gA, 256, 0, stream>>>(ptr, recs, dinv, bc1, (const uint4*)tb,
                                  (float4*)bufA, N);

    // --- conv2 ---
    k_conv<<<gG, 256, 0, stream>>>(bufA, Wc2, dinv, tb, N);
    k_agg<<<gA, 256, 0, stream>>>(ptr, recs, dinv, bc2, (const uint4*)tb,
                                  (float4*)bufA, N);

    // --- out = agg2 @ W2 + b2 ---
    k_final<<<gG, 256, 0, stream>>>(bufA, W2, b2, out, N);
}